// Round 5
// baseline (424.106 us; speedup 1.0000x reference)
//
#include <hip/hip_runtime.h>
#include <stdint.h>

#define Bn 4
#define Cn 512
#define Tn 4096
#define Kn 256
#define Nall 768

typedef __attribute__((ext_vector_type(8))) short bf16x8;
typedef __attribute__((ext_vector_type(4))) float f32x4;

__device__ __forceinline__ unsigned short f2bf(float f) {
  union { float f; unsigned int u; } v; v.f = f;
  unsigned int r = v.u + 0x7fffu + ((v.u >> 16) & 1u);
  return (unsigned short)(r >> 16);
}

__device__ __forceinline__ float bf2f(unsigned short h) {
  union { unsigned int u; float f; } v; v.u = ((unsigned int)h) << 16; return v.f;
}

__device__ __forceinline__ void gload_lds16(const void* g, void* l) {
  auto gp = reinterpret_cast<const __attribute__((address_space(1))) unsigned int*>(
      reinterpret_cast<uintptr_t>(g));
  auto lp = reinterpret_cast<__attribute__((address_space(3))) unsigned int*>(
      static_cast<unsigned int>(reinterpret_cast<uintptr_t>(l)));
  __builtin_amdgcn_global_load_lds(gp, lp, 16, 0, 0);
}

__device__ __forceinline__ f32x4 mfma16(bf16x8 a, bf16x8 b, f32x4 c) {
  return __builtin_amdgcn_mfma_f32_16x16x32_bf16(a, b, c, 0, 0, 0);
}

// ---------------------------------------------------------------------------
// prep_x: fp32 passthrough copy into out rows [0,512) + transpose to x_t bf16 (B,T,C)
// ---------------------------------------------------------------------------
__global__ __launch_bounds__(256) void prep_x_kernel(const float* __restrict__ x,
    float* __restrict__ out, unsigned short* __restrict__ xt) {
  const int tt = blockIdx.x, cc = blockIdx.y, b = blockIdx.z;
  __shared__ unsigned short tile[64][66];
  const int tid = threadIdx.x;
#pragma unroll
  for (int e = 0; e < 4; ++e) {
    int f = e * 256 + tid;
    int row = f >> 4, c4 = f & 15;
    size_t gi = ((size_t)(b * Cn + cc * 64 + row)) * Tn + tt * 64 + c4 * 4;
    float4 v = *(const float4*)(x + gi);
    size_t go = ((size_t)(b * Nall + cc * 64 + row)) * Tn + tt * 64 + c4 * 4;
    *(float4*)(out + go) = v;
    tile[row][c4 * 4 + 0] = f2bf(v.x);
    tile[row][c4 * 4 + 1] = f2bf(v.y);
    tile[row][c4 * 4 + 2] = f2bf(v.z);
    tile[row][c4 * 4 + 3] = f2bf(v.w);
  }
  __syncthreads();
#pragma unroll
  for (int e = 0; e < 2; ++e) {
    int f = e * 256 + tid;
    int trow = f >> 3, cv = f & 7;
    bf16x8 vv;
#pragma unroll
    for (int j = 0; j < 8; ++j) vv[j] = (short)tile[cv * 8 + j][trow];
    *(bf16x8*)(xt + ((size_t)(b * Tn) + tt * 64 + trow) * Cn + cc * 64 + cv * 8) = vv;
  }
}

// ---------------------------------------------------------------------------
// prep_w: W^T bf16 (768 x 512); bias concat
// ---------------------------------------------------------------------------
__global__ __launch_bounds__(256) void prep_w_kernel(const float* __restrict__ Wq,
    const float* __restrict__ Wk, const float* __restrict__ Wv,
    const float* __restrict__ bq, const float* __restrict__ bk, const float* __restrict__ bv,
    unsigned short* __restrict__ wt, float* __restrict__ bias) {
  int idx = blockIdx.x * 256 + threadIdx.x;
  int n = idx >> 9, c = idx & 511;
  const float* W = (n < 256) ? Wq : ((n < 512) ? Wk : Wv);
  wt[idx] = f2bf(W[c * 256 + (n & 255)]);
  if (idx < Nall) {
    const float* bb = (idx < 256) ? bq : ((idx < 512) ? bk : bv);
    bias[idx] = bb[idx & 255];
  }
}

// ---------------------------------------------------------------------------
// qkv_gemm: 128x128 tile, BK=32, m97 structure (unchanged).
// ---------------------------------------------------------------------------
__global__ __launch_bounds__(256) void qkv_gemm_kernel(const unsigned short* __restrict__ xt,
    const unsigned short* __restrict__ wt, const float* __restrict__ bias,
    unsigned short* __restrict__ qb, unsigned short* __restrict__ kb,
    unsigned short* __restrict__ vt) {
  const int t0 = blockIdx.x * 128, n0 = blockIdx.y * 128, b = blockIdx.z;
  __shared__ char at[8192];
  __shared__ char bt[8192];
  const int tid = threadIdx.x, w = tid >> 6, lane = tid & 63, g = lane >> 4, lr = lane & 15;
  const int wm = w >> 1, wn = w & 1;
  f32x4 acc[4][4];
#pragma unroll
  for (int i = 0; i < 4; ++i)
#pragma unroll
    for (int j = 0; j < 4; ++j) acc[i][j] = (f32x4){0.f, 0.f, 0.f, 0.f};

  const unsigned short* xtp = xt + ((size_t)b * Tn + t0) * Cn;
  for (int c0 = 0; c0 < Cn; c0 += 32) {
    __syncthreads();
#pragma unroll
    for (int i = 0; i < 2; ++i) {
      int off = i * 4096 + w * 1024 + lane * 16;
      int row = off >> 6, col = off & 63;
      gload_lds16(xtp + (size_t)row * Cn + c0 + (col >> 1), at + i * 4096 + w * 1024);
      gload_lds16(wt + (size_t)(n0 + row) * Cn + c0 + (col >> 1), bt + i * 4096 + w * 1024);
    }
    __syncthreads();
    bf16x8 af[4], bfr[4];
#pragma unroll
    for (int mt = 0; mt < 4; ++mt)
      af[mt] = *(const bf16x8*)(at + (wm * 64 + mt * 16 + lr) * 64 + g * 16);
#pragma unroll
    for (int nt = 0; nt < 4; ++nt)
      bfr[nt] = *(const bf16x8*)(bt + (wn * 64 + nt * 16 + lr) * 64 + g * 16);
#pragma unroll
    for (int mt = 0; mt < 4; ++mt)
#pragma unroll
      for (int nt = 0; nt < 4; ++nt)
        acc[mt][nt] = mfma16(af[mt], bfr[nt], acc[mt][nt]);
  }
#pragma unroll
  for (int nt = 0; nt < 4; ++nt) {
    int n = n0 + wn * 64 + nt * 16 + lr;
    float bval = bias[n];
#pragma unroll
    for (int mt = 0; mt < 4; ++mt) {
#pragma unroll
      for (int r = 0; r < 4; ++r) {
        int t = t0 + wm * 64 + mt * 16 + g * 4 + r;
        unsigned short h = f2bf(acc[mt][nt][r] + bval);
        if (n < 256) {
          qb[((size_t)(b * Tn) + t) * Kn + n] = h;
        } else if (n < 512) {
          int nc = n - 256;
          kb[((size_t)(b * Tn) + t) * Kn + (nc ^ ((t & 7) << 3))] = h;
        } else {
          int vc = n - 512;
          int tl = t & 63;
          vt[((size_t)(b * Kn) + vc) * Tn + (t & ~63) + (tl ^ ((vc & 7) << 3))] = h;
        }
      }
    }
  }
}

// ---------------------------------------------------------------------------
// attn: split-KV flash causal attention.
// 4 waves x 32 q-rows = 128 q/block; each K/V fragment feeds 2 MFMAs (two
// row-tiles mt=0,1 from registers) -> LDS bytes per FLOP halved vs round 4.
// Row-sums l via MFMA ones-column (no sum shuffles); defer-max (THR=8 base-2)
// skips rescale; fully-masked waves skip compute. Single-buffered K/V 64KB +
// P 16KB = 80KB LDS -> 2 blocks/CU; cross-block overlap hides stage drain.
// chunk = 8 s-tiles -> 576 blocks; partials po in bf16 (560 x 64KB).
// ---------------------------------------------------------------------------
__global__ __launch_bounds__(256, 2) void attn_kernel(const unsigned short* __restrict__ qb,
    const unsigned short* __restrict__ kb, const unsigned short* __restrict__ vt,
    unsigned short* __restrict__ po, float* __restrict__ ml, float* __restrict__ out) {
  const int wg = blockIdx.x;
  const int b = (wg >> 1) & 3;                // batch -> XCD pair
  int item = ((wg >> 3) << 1) | (wg & 1);     // [0,144)
  item = (item * 59) % 144;                   // bijective scramble
  int t = 0, c = 0, preP = 0, accum = 0;
  for (t = 0; t < 32; ++t) {
    int cnt = (t + 4) >> 2;                   // ceil((2t+2)/8)
    if (item < accum + cnt) { c = item - accum; break; }
    accum += cnt;
    if (t >= 4) preP += cnt;
  }
  const bool direct = (t < 4);
  const int slot = b * 140 + preP + c;
  const int qt0 = t << 7;
  const int sb = c * 8, se = min(sb + 8, 2 * t + 2);

  __shared__ char smem[81920];
  char* kbuf = smem;             // [64][512B] swizzled K
  char* vbuf = smem + 32768;     // [256][128B] swizzled V^T
  char* pbuf = smem + 65536;     // 4 waves x 4096 (2 mt x 2048)
  const int tid = threadIdx.x, w = tid >> 6, lane = tid & 63, g = lane >> 4, lr = lane & 15;
  const float SCL = 0.09016844005555521f;   // log2(e)/sqrt(256)
  const int wrow0 = qt0 + w * 32;

  const unsigned short* kbp = kb + (size_t)(b * Tn) * Kn;
  const unsigned short* vtp = vt + (size_t)(b * Kn) * Tn;

  bf16x8 qf[2][8];
#pragma unroll
  for (int mt = 0; mt < 2; ++mt) {
    const unsigned short* qrow = qb + ((size_t)(b * Tn) + wrow0 + mt * 16 + lr) * Kn;
#pragma unroll
    for (int kc = 0; kc < 8; ++kc) qf[mt][kc] = *(const bf16x8*)(qrow + kc * 32 + g * 8);
  }

  bf16x8 onef;
#pragma unroll
  for (int j = 0; j < 8; ++j) onef[j] = (short)0x3F80;   // bf16 1.0

  f32x4 o[2][16];
#pragma unroll
  for (int mt = 0; mt < 2; ++mt)
#pragma unroll
    for (int nt = 0; nt < 16; ++nt) o[mt][nt] = (f32x4){0.f, 0.f, 0.f, 0.f};
  float m2[2][4], ls[2][4];
#pragma unroll
  for (int mt = 0; mt < 2; ++mt)
#pragma unroll
    for (int r = 0; r < 4; ++r) { m2[mt][r] = -1e30f; ls[mt][r] = 0.f; }
  char* pbw = pbuf + w * 4096;

  for (int s = sb; s < se; ++s) {
    const int s0 = s * 64;
    __syncthreads();   // prev-step LDS reads complete
#pragma unroll
    for (int i2 = 0; i2 < 8; ++i2) {
      int off = i2 * 4096 + tid * 16;
      { int row = off >> 9, col = off & 511;
        gload_lds16(kbp + (size_t)(s0 + row) * Kn + (col >> 1), kbuf + off); }
      { int row = off >> 7, col = off & 127;
        gload_lds16(vtp + (size_t)row * Tn + s0 + (col >> 1), vbuf + off); }
    }
    __syncthreads();   // staged (vmcnt drain)

    if (s0 < wrow0 + 32) {   // wave has at least one unmasked row
      // QK^T : S[32q][64s], kf shared across mt
      f32x4 sfr[2][4];
#pragma unroll
      for (int mt = 0; mt < 2; ++mt)
#pragma unroll
        for (int ct = 0; ct < 4; ++ct) sfr[mt][ct] = (f32x4){0.f, 0.f, 0.f, 0.f};
#pragma unroll
      for (int kc = 0; kc < 8; ++kc) {
#pragma unroll
        for (int ct = 0; ct < 4; ++ct) {
          int srow = ct * 16 + lr;
          bf16x8 kf = *(const bf16x8*)(kbuf + srow * 512 +
                                       ((kc * 64 + g * 16) ^ ((srow & 7) << 4)));
          sfr[0][ct] = mfma16(qf[0][kc], kf, sfr[0][ct]);
          sfr[1][ct] = mfma16(qf[1][kc], kf, sfr[1][ct]);
        }
      }

      const bool needmask = (s0 + 64 > wrow0);
#pragma unroll
      for (int mt = 0; mt < 2; ++mt) {
        float sv[4][4];
#pragma unroll
        for (int ct = 0; ct < 4; ++ct)
#pragma unroll
          for (int r = 0; r < 4; ++r) {
            float v = sfr[mt][ct][r] * SCL;
            if (needmask) {
              int trow = wrow0 + mt * 16 + g * 4 + r;
              int scol = s0 + ct * 16 + lr;
              if (scol > trow) v = -1e30f;
            }
            sv[ct][r] = v;
          }
        float mx[4];
#pragma unroll
        for (int r = 0; r < 4; ++r)
          mx[r] = fmaxf(fmaxf(sv[0][r], sv[1][r]), fmaxf(sv[2][r], sv[3][r]));
#pragma unroll
        for (int d = 1; d < 16; d <<= 1)
#pragma unroll
          for (int r = 0; r < 4; ++r)
            mx[r] = fmaxf(mx[r], __shfl_xor(mx[r], d, 64));
        // defer-max: only rescale when some row's max grew past threshold
        int stable = 1;
#pragma unroll
        for (int r = 0; r < 4; ++r) stable &= (mx[r] <= m2[mt][r] + 8.0f);
        if (!__all(stable)) {
#pragma unroll
          for (int r = 0; r < 4; ++r) {
            float mn = fmaxf(m2[mt][r], mx[r]);
            float al = __builtin_amdgcn_exp2f(m2[mt][r] - mn);
            m2[mt][r] = mn;
            ls[mt][r] *= al;
#pragma unroll
            for (int nt = 0; nt < 16; ++nt) o[mt][nt][r] *= al;
          }
        }
        unsigned short ph[4][4];
#pragma unroll
        for (int ct = 0; ct < 4; ++ct)
#pragma unroll
          for (int r = 0; r < 4; ++r)
            ph[ct][r] = f2bf(__builtin_amdgcn_exp2f(sv[ct][r] - m2[mt][r]));
#pragma unroll
        for (int ct = 0; ct < 4; ++ct)
#pragma unroll
          for (int r = 0; r < 4; ++r) {
            int row = g * 4 + r;
            int colb = (ct * 16 + lr) * 2;
            *(unsigned short*)(pbw + mt * 2048 + row * 128 + (colb ^ ((row & 7) << 4))) = ph[ct][r];
          }
      }

      // PV + row-sum-via-ones
      bf16x8 pa[2][2];
#pragma unroll
      for (int mt = 0; mt < 2; ++mt)
#pragma unroll
        for (int kc2 = 0; kc2 < 2; ++kc2)
          pa[mt][kc2] = *(const bf16x8*)(pbw + mt * 2048 + lr * 128 +
                                         ((kc2 * 64 + g * 16) ^ ((lr & 7) << 4)));
      f32x4 lacc[2];
      lacc[0] = (f32x4){0.f, 0.f, 0.f, 0.f};
      lacc[1] = (f32x4){0.f, 0.f, 0.f, 0.f};
#pragma unroll
      for (int kc2 = 0; kc2 < 2; ++kc2) {
        lacc[0] = mfma16(pa[0][kc2], onef, lacc[0]);
        lacc[1] = mfma16(pa[1][kc2], onef, lacc[1]);
      }
#pragma unroll
      for (int nt = 0; nt < 16; ++nt) {
        int vrow = nt * 16 + lr;
#pragma unroll
        for (int kc2 = 0; kc2 < 2; ++kc2) {
          bf16x8 vf = *(const bf16x8*)(vbuf + vrow * 128 +
                                       ((kc2 * 64 + g * 16) ^ ((vrow & 7) << 4)));
          o[0][nt] = mfma16(pa[0][kc2], vf, o[0][nt]);
          o[1][nt] = mfma16(pa[1][kc2], vf, o[1][nt]);
        }
      }
#pragma unroll
      for (int mt = 0; mt < 2; ++mt)
#pragma unroll
        for (int r = 0; r < 4; ++r) ls[mt][r] += lacc[mt][r];
    }
  }

  if (direct) {
    float* outp = out + ((size_t)(b * Nall) + 512) * Tn;
#pragma unroll
    for (int mt = 0; mt < 2; ++mt) {
      float inv[4];
#pragma unroll
      for (int r = 0; r < 4; ++r) inv[r] = 1.0f / ls[mt][r];
#pragma unroll
      for (int nt = 0; nt < 16; ++nt)
#pragma unroll
        for (int r = 0; r < 4; ++r)
          outp[(size_t)(nt * 16 + lr) * Tn + wrow0 + mt * 16 + g * 4 + r] = o[mt][nt][r] * inv[r];
    }
  } else {
    unsigned short* pob = po + (size_t)slot * 32768;
#pragma unroll
    for (int mt = 0; mt < 2; ++mt)
#pragma unroll
      for (int nt = 0; nt < 16; ++nt)
#pragma unroll
        for (int r = 0; r < 4; ++r)
          pob[(w * 32 + mt * 16 + g * 4 + r) * 256 + nt * 16 + lr] = f2bf(o[mt][nt][r]);
    if (lr == 0) {
#pragma unroll
      for (int mt = 0; mt < 2; ++mt)
#pragma unroll
        for (int r = 0; r < 4; ++r) {
          int row = w * 32 + mt * 16 + g * 4 + r;
          ml[(size_t)slot * 256 + row] = m2[mt][r];
          ml[(size_t)slot * 256 + 128 + row] = ls[mt][r];
        }
    }
  }
}

// ---------------------------------------------------------------------------
// merge: per (tile t>=4, batch, 32-row group): merge scalars to LDS once,
// then weighted-sum bf16 partials, write float4 along t.
// ---------------------------------------------------------------------------
__global__ __launch_bounds__(256) void merge_kernel(const unsigned short* __restrict__ po,
    const float* __restrict__ ml, float* __restrict__ out) {
  const int tt = blockIdx.x + 4;              // tile [4,32)
  const int b = blockIdx.y, zg = blockIdx.z;  // row-group [0,4)
  const int nc = (tt + 4) >> 2;               // chunks, <=8
  int preP = 0;
  for (int u = 4; u < tt; ++u) preP += (u + 4) >> 2;
  const int slot0 = b * 140 + preP;
  const int tid = threadIdx.x;

  __shared__ float wrow[32][8];
  if (tid < 32) {
    int r = zg * 32 + tid;
    float M = -1e30f;
    for (int cc = 0; cc < nc; ++cc)
      M = fmaxf(M, ml[(size_t)(slot0 + cc) * 256 + r]);
    float L = 0.f;
    for (int cc = 0; cc < nc; ++cc) {
      float e = __builtin_amdgcn_exp2f(ml[(size_t)(slot0 + cc) * 256 + r] - M);
      wrow[tid][cc] = e;
      L += ml[(size_t)(slot0 + cc) * 256 + 128 + r] * e;
    }
    float linv = 1.0f / L;
    for (int cc = 0; cc < nc; ++cc) wrow[tid][cc] *= linv;
  }
  __syncthreads();

  const int n = tid;
  float* outp = out + ((size_t)(b * Nall + 512 + n)) * Tn + tt * 128 + zg * 32;
  for (int r4 = 0; r4 < 8; ++r4) {
    float4 vv;
#pragma unroll
    for (int j = 0; j < 4; ++j) {
      int rl = r4 * 4 + j;
      int rr = zg * 32 + rl;
      float val = 0.f;
      for (int cc = 0; cc < nc; ++cc)
        val += wrow[rl][cc] * bf2f(po[(size_t)(slot0 + cc) * 32768 + rr * 256 + n]);
      vv[j] = val;
    }
    *(float4*)(outp + r4 * 4) = vv;
  }
}

// ---------------------------------------------------------------------------
extern "C" void kernel_launch(void* const* d_in, const int* in_sizes, int n_in,
                              void* d_out, int out_size, void* d_ws, size_t ws_size,
                              hipStream_t stream) {
  const float* x  = (const float*)d_in[0];
  const float* Wq = (const float*)d_in[1];
  const float* bq = (const float*)d_in[2];
  const float* Wk = (const float*)d_in[3];
  const float* bk = (const float*)d_in[4];
  const float* Wv = (const float*)d_in[5];
  const float* bv = (const float*)d_in[6];
  float* out = (float*)d_out;
  char* ws = (char*)d_ws;

  // layout (max end 62,439,424 B < proven-safe 63,209,472):
  unsigned short* qb = (unsigned short*)(ws);                 //  8,388,608
  unsigned short* kb = (unsigned short*)(ws + 8388608);       //  8,388,608
  unsigned short* vt = (unsigned short*)(ws + 16777216);      //  8,388,608
  unsigned short* xt = (unsigned short*)(ws + 25165824);      // 16,777,216 (dead after gemm)
  unsigned short* wt = (unsigned short*)(ws + 41943040);      //    786,432 (dead after gemm)
  float*        bias = (float*)(ws + 42729472);               //      3,072 (dead after gemm)
  unsigned short* po = (unsigned short*)(ws + 25165824);      // 36,700,160 = 560 x 64KB bf16 (overlaps xt/wt/bias)
  float*         mlb = (float*)(ws + 61865984);               //    573,440 (ends 62,439,424)

  prep_w_kernel<<<1536, 256, 0, stream>>>(Wq, Wk, Wv, bq, bk, bv, wt, bias);
  prep_x_kernel<<<dim3(64, 8, 4), 256, 0, stream>>>(x, out, xt);
  qkv_gemm_kernel<<<dim3(32, 6, 4), 256, 0, stream>>>(xt, wt, bias, qb, kb, vt);
  attn_kernel<<<576, 256, 0, stream>>>(qb, kb, vt, po, mlb, out);
  merge_kernel<<<dim3(28, 4, 4), 256, 0, stream>>>(po, mlb, out);
}

// Round 7
// 360.235 us; speedup vs baseline: 1.1773x; 1.1773x over previous
//
#include <hip/hip_runtime.h>
#include <stdint.h>

#define Bn 4
#define Cn 512
#define Tn 4096
#define Kn 256
#define Nall 768

typedef __attribute__((ext_vector_type(8))) short bf16x8;
typedef __attribute__((ext_vector_type(4))) float f32x4;
typedef __attribute__((ext_vector_type(16))) float f32x16;

__device__ __forceinline__ unsigned short f2bf(float f) {
  union { float f; unsigned int u; } v; v.f = f;
  unsigned int r = v.u + 0x7fffu + ((v.u >> 16) & 1u);
  return (unsigned short)(r >> 16);
}

__device__ __forceinline__ float bf2f(unsigned short h) {
  union { unsigned int u; float f; } v; v.u = ((unsigned int)h) << 16; return v.f;
}

__device__ __forceinline__ void gload_lds16(const void* g, void* l) {
  auto gp = reinterpret_cast<const __attribute__((address_space(1))) unsigned int*>(
      reinterpret_cast<uintptr_t>(g));
  auto lp = reinterpret_cast<__attribute__((address_space(3))) unsigned int*>(
      static_cast<unsigned int>(reinterpret_cast<uintptr_t>(l)));
  __builtin_amdgcn_global_load_lds(gp, lp, 16, 0, 0);
}

__device__ __forceinline__ f32x4 mfma16(bf16x8 a, bf16x8 b, f32x4 c) {
  return __builtin_amdgcn_mfma_f32_16x16x32_bf16(a, b, c, 0, 0, 0);
}
__device__ __forceinline__ f32x16 mfma32(bf16x8 a, bf16x8 b, f32x16 c) {
  return __builtin_amdgcn_mfma_f32_32x32x16_bf16(a, b, c, 0, 0, 0);
}

// ---------------------------------------------------------------------------
// prep_x: fp32 passthrough copy into out rows [0,512) + transpose to x_t bf16 (B,T,C)
// ---------------------------------------------------------------------------
__global__ __launch_bounds__(256) void prep_x_kernel(const float* __restrict__ x,
    float* __restrict__ out, unsigned short* __restrict__ xt) {
  const int tt = blockIdx.x, cc = blockIdx.y, b = blockIdx.z;
  __shared__ unsigned short tile[64][66];
  const int tid = threadIdx.x;
#pragma unroll
  for (int e = 0; e < 4; ++e) {
    int f = e * 256 + tid;
    int row = f >> 4, c4 = f & 15;
    size_t gi = ((size_t)(b * Cn + cc * 64 + row)) * Tn + tt * 64 + c4 * 4;
    float4 v = *(const float4*)(x + gi);
    size_t go = ((size_t)(b * Nall + cc * 64 + row)) * Tn + tt * 64 + c4 * 4;
    *(float4*)(out + go) = v;
    tile[row][c4 * 4 + 0] = f2bf(v.x);
    tile[row][c4 * 4 + 1] = f2bf(v.y);
    tile[row][c4 * 4 + 2] = f2bf(v.z);
    tile[row][c4 * 4 + 3] = f2bf(v.w);
  }
  __syncthreads();
#pragma unroll
  for (int e = 0; e < 2; ++e) {
    int f = e * 256 + tid;
    int trow = f >> 3, cv = f & 7;
    bf16x8 vv;
#pragma unroll
    for (int j = 0; j < 8; ++j) vv[j] = (short)tile[cv * 8 + j][trow];
    *(bf16x8*)(xt + ((size_t)(b * Tn) + tt * 64 + trow) * Cn + cc * 64 + cv * 8) = vv;
  }
}

// ---------------------------------------------------------------------------
// prep_w: W^T bf16 (768 x 512); bias concat
// ---------------------------------------------------------------------------
__global__ __launch_bounds__(256) void prep_w_kernel(const float* __restrict__ Wq,
    const float* __restrict__ Wk, const float* __restrict__ Wv,
    const float* __restrict__ bq, const float* __restrict__ bk, const float* __restrict__ bv,
    unsigned short* __restrict__ wt, float* __restrict__ bias) {
  int idx = blockIdx.x * 256 + threadIdx.x;
  int n = idx >> 9, c = idx & 511;
  const float* W = (n < 256) ? Wq : ((n < 512) ? Wk : Wv);
  wt[idx] = f2bf(W[c * 256 + (n & 255)]);
  if (idx < Nall) {
    const float* bb = (idx < 256) ? bq : ((idx < 512) ? bk : bv);
    bias[idx] = bb[idx & 255];
  }
}

// ---------------------------------------------------------------------------
// qkv_gemm: 128x128 tile, BK=32, m97 structure. Epilogue writes:
//   qb[t][k]                          (plain)
//   kbT[b][kg=k>>3][t][k&7]           (staging-order for attn K tiles)
//   vS [b][t>>6][(t&63)>>3][v][t&7]   (staging-order for attn V tiles)
// ---------------------------------------------------------------------------
__global__ __launch_bounds__(256) void qkv_gemm_kernel(const unsigned short* __restrict__ xt,
    const unsigned short* __restrict__ wt, const float* __restrict__ bias,
    unsigned short* __restrict__ qb, unsigned short* __restrict__ kbT,
    unsigned short* __restrict__ vS) {
  const int t0 = blockIdx.x * 128, n0 = blockIdx.y * 128, b = blockIdx.z;
  __shared__ char at[8192];
  __shared__ char bt[8192];
  const int tid = threadIdx.x, w = tid >> 6, lane = tid & 63, g = lane >> 4, lr = lane & 15;
  const int wm = w >> 1, wn = w & 1;
  f32x4 acc[4][4];
#pragma unroll
  for (int i = 0; i < 4; ++i)
#pragma unroll
    for (int j = 0; j < 4; ++j) acc[i][j] = (f32x4){0.f, 0.f, 0.f, 0.f};

  const unsigned short* xtp = xt + ((size_t)b * Tn + t0) * Cn;
  for (int c0 = 0; c0 < Cn; c0 += 32) {
    __syncthreads();
#pragma unroll
    for (int i = 0; i < 2; ++i) {
      int off = i * 4096 + w * 1024 + lane * 16;
      int row = off >> 6, col = off & 63;
      gload_lds16(xtp + (size_t)row * Cn + c0 + (col >> 1), at + i * 4096 + w * 1024);
      gload_lds16(wt + (size_t)(n0 + row) * Cn + c0 + (col >> 1), bt + i * 4096 + w * 1024);
    }
    __syncthreads();
    bf16x8 af[4], bfr[4];
#pragma unroll
    for (int mt = 0; mt < 4; ++mt)
      af[mt] = *(const bf16x8*)(at + (wm * 64 + mt * 16 + lr) * 64 + g * 16);
#pragma unroll
    for (int nt = 0; nt < 4; ++nt)
      bfr[nt] = *(const bf16x8*)(bt + (wn * 64 + nt * 16 + lr) * 64 + g * 16);
#pragma unroll
    for (int mt = 0; mt < 4; ++mt)
#pragma unroll
      for (int nt = 0; nt < 4; ++nt)
        acc[mt][nt] = mfma16(af[mt], bfr[nt], acc[mt][nt]);
  }
#pragma unroll
  for (int nt = 0; nt < 4; ++nt) {
    int n = n0 + wn * 64 + nt * 16 + lr;
    float bval = bias[n];
#pragma unroll
    for (int mt = 0; mt < 4; ++mt) {
#pragma unroll
      for (int r = 0; r < 4; ++r) {
        int t = t0 + wm * 64 + mt * 16 + g * 4 + r;
        unsigned short h = f2bf(acc[mt][nt][r] + bval);
        if (n < 256) {
          qb[((size_t)(b * Tn) + t) * Kn + n] = h;
        } else if (n < 512) {
          int nc = n - 256;
          kbT[(((size_t)(b * 32 + (nc >> 3))) * Tn + t) * 8 + (nc & 7)] = h;
        } else {
          int vc = n - 512;
          vS[(((size_t)(b * 64 + (t >> 6))) * 2048 + ((t & 63) >> 3) * 256 + vc) * 8 + (t & 7)] = h;
        }
      }
    }
  }
}

// ---------------------------------------------------------------------------
// attn: split-KV flash causal attention, 32x32x16 MFMA.
// 8 waves x 32 q-rows = 256 q/block. Tile t in [0,16) has 4t+4 s-tiles of 64;
// chunks of 8 steps: 256 full-8 blocks first (1/CU), 32 len-4 tails backfill.
// K/V dbuf, 1 barrier/step (stage s+1 issued pre-compute). Fixed-shift
// softmax p = exp2(s*SCL - 32) (exact: merge divides by matching l-sum);
// l via ones-column MFMA. LDS: K [kg32][s64][16B], V [vg8][v256][16B] staged
// linearly from pre-arranged kbT/vS (fully coalesced); P XOR-chunk swizzle,
// SAME bijection on write and read. LDS = 160 KB, 1 block/CU, 8 waves.
// ---------------------------------------------------------------------------
#define STAGE(s_, par_) do {                                                    \
    char* kd_ = kbase + (par_) * 32768;                                         \
    char* vd_ = vbase + (par_) * 32768;                                         \
    const unsigned short* ksrc_ = kbp + (size_t)(s_) * 512;                     \
    const unsigned short* vsrc_ = vtp + (size_t)(s_) * 16384;                   \
    _Pragma("unroll")                                                           \
    for (int i_ = 0; i_ < 4; ++i_) {                                            \
      int g16_ = i_ * 512 + tid;                                                \
      int kg_ = g16_ >> 6, ksr_ = g16_ & 63;                                    \
      gload_lds16(ksrc_ + ((size_t)kg_ * Tn + ksr_) * 8, kd_ + g16_ * 16);      \
      gload_lds16(vsrc_ + (size_t)g16_ * 8, vd_ + g16_ * 16);                   \
    }                                                                           \
  } while (0)

__global__ __launch_bounds__(512, 2) void attn_kernel(const unsigned short* __restrict__ qb,
    const unsigned short* __restrict__ kbT, const unsigned short* __restrict__ vS,
    unsigned short* __restrict__ po, float* __restrict__ ml) {
  const int wg = blockIdx.x;
  const int b = wg & 3;                      // batch -> XCD spread
  int t = 0, c = 0, pre = 0;
  if (wg < 256) {                            // full-8 chunks
    int f = wg >> 2, acc = 0;
    for (int u = 0; u < 16; ++u) {
      int nfull = (u & 1) ? ((u + 1) >> 1) : (u >> 1);
      if (f < acc + nfull) { t = u; c = f - acc; break; }
      acc += nfull;
      pre += (u + 2) >> 1;
    }
  } else {                                   // len-4 tails (even tiles)
    int j = (wg - 256) >> 2;
    t = 2 * j; c = t >> 1;
    for (int u = 0; u < t; ++u) pre += (u + 2) >> 1;
  }
  const int slot = b * 72 + pre + c;
  const int qt0 = t << 8;
  const int sb = c * 8, se = min(sb + 8, 4 * t + 4);

  __shared__ char smem[163840];
  char* kbase = smem;            // 2 x 32768
  char* vbase = smem + 65536;    // 2 x 32768
  char* pbuf  = smem + 131072;   // 8 waves x 4096
  const int tid = threadIdx.x, w = tid >> 6, lane = tid & 63;
  const int lo = lane & 31, hi = lane >> 5;
  const float SCL = 0.09016844005555521f;    // log2(e)/sqrt(256)
  const int wrow0 = qt0 + w * 32;
  const int kofs = hi * 1024 + lo * 16;
  const int vofs = hi * 4096 + lo * 16;
  char* pbase = pbuf + w * 4096;

  const unsigned short* kbp = kbT + (size_t)b * (32 * Tn * 8);
  const unsigned short* vtp = vS + (size_t)b * (64 * 2048 * 8);

  // Q fragments (32x32x16 A): row = lane&31, k = (lane>>5)*8 + e, per 16-k step
  const unsigned short* qrow = qb + ((size_t)(b * Tn) + wrow0 + lo) * Kn + hi * 8;
  bf16x8 qf[16];
#pragma unroll
  for (int ks = 0; ks < 16; ++ks) qf[ks] = *(const bf16x8*)(qrow + ks * 16);

  bf16x8 onef;
#pragma unroll
  for (int j = 0; j < 8; ++j) onef[j] = (short)0x3F80;   // bf16 1.0

  f32x16 zv;
#pragma unroll
  for (int e = 0; e < 16; ++e) zv[e] = 0.f;
  f32x16 o[8];
#pragma unroll
  for (int ct8 = 0; ct8 < 8; ++ct8) o[ct8] = zv;
  f32x16 lacc = zv;

  STAGE(sb, 0);
  __syncthreads();
  int cur = 0;
  for (int s = sb; s < se; ++s) {
    const int s0 = s * 64;
    if (s + 1 < se) STAGE(s + 1, cur ^ 1);   // issue next tile BEFORE compute
    char* kcur = kbase + cur * 32768;
    char* vcur = vbase + cur * 32768;
    const bool active = (s0 <= wrow0 + 31);

    if (active) {
      const bool needmask = (s0 + 63 > wrow0);
      // QK^T, ct-outer: S[32q][64s]
#pragma unroll
      for (int ct = 0; ct < 2; ++ct) {
        f32x16 sfr = zv;
#pragma unroll
        for (int ks = 0; ks < 16; ++ks) {
          bf16x8 kf = *(const bf16x8*)(kcur + ks * 2048 + ct * 512 + kofs);
          sfr = mfma32(qf[ks], kf, sfr);
        }
        // fixed-shift softmax + P-write; chunk = (s3b*32 + crow) ^ (s3b&7)
        const int scol = s0 + ct * 32 + lo;
        const int s3b = ct * 4 + (lo >> 3);
        const int key = s3b & 7;
        const int bofs = (lo & 7) * 2;
#pragma unroll
        for (int j = 0; j < 16; ++j) {
          int crow = (j & 3) + 8 * (j >> 2) + 4 * hi;
          float e = sfr[j] * SCL - 32.0f;
          if (needmask && (scol > wrow0 + crow)) e = -1e30f;
          float p = __builtin_amdgcn_exp2f(e);
          int chunk = (s3b * 32 + crow) ^ key;
          *(unsigned short*)(pbase + (chunk << 4) + bofs) = f2bf(p);
        }
      }
      // PV, ks-outer (single live pa): same chunk bijection on read
#pragma unroll
      for (int ks = 0; ks < 4; ++ks) {
        int s3 = ks * 2 + hi;
        bf16x8 pa = *(const bf16x8*)(pbase + ((((s3 * 32 + lo) ^ (s3 & 7))) << 4));
        lacc = mfma32(pa, onef, lacc);
#pragma unroll
        for (int ct8 = 0; ct8 < 8; ++ct8) {
          bf16x8 vf = *(const bf16x8*)(vcur + ks * 8192 + ct8 * 512 + vofs);
          o[ct8] = mfma32(pa, vf, o[ct8]);
        }
      }
    }
    __syncthreads();   // drains this step's stage after compute
    cur ^= 1;
  }

  // epilogue: unnormalized o (bf16) + l per row (shared fixed shift)
  unsigned short* pob = po + (size_t)slot * 65536;
#pragma unroll
  for (int ct8 = 0; ct8 < 8; ++ct8) {
#pragma unroll
    for (int j = 0; j < 16; ++j) {
      int crow = (j & 3) + 8 * (j >> 2) + 4 * hi;
      pob[(size_t)(w * 32 + crow) * 256 + ct8 * 32 + lo] = f2bf(o[ct8][j]);
    }
  }
  if (lo == 0) {
#pragma unroll
    for (int j = 0; j < 16; ++j) {
      int crow = (j & 3) + 8 * (j >> 2) + 4 * hi;
      ml[(size_t)slot * 256 + w * 32 + crow] = lacc[j];
    }
  }
}

// ---------------------------------------------------------------------------
// merge: out[b, 512+v, qt0+q] = (sum_c po_c[q][v]) / (sum_c l_c[q]).
// Plain sums (all partials share the fixed shift). v-split grid; bf16x8 loads;
// stores coalesced across threads (q contiguous).
// ---------------------------------------------------------------------------
__global__ __launch_bounds__(256) void merge_kernel(const unsigned short* __restrict__ po,
    const float* __restrict__ ml, float* __restrict__ out) {
  const int tt = blockIdx.x, b = blockIdx.y, vq = blockIdx.z;
  const int nc = (tt + 2) >> 1;
  int pre = 0;
  for (int u = 0; u < tt; ++u) pre += (u + 2) >> 1;
  const int slot0 = b * 72 + pre;
  const int q = threadIdx.x;

  float L = 0.f;
  for (int cc = 0; cc < nc; ++cc) L += ml[(size_t)(slot0 + cc) * 256 + q];
  const float linv = 1.0f / L;

  const unsigned short* pq = po + (size_t)slot0 * 65536 + q * 256 + vq * 64;
  float* outp = out + ((size_t)(b * Nall + 512 + vq * 64)) * Tn + tt * 256 + q;
  for (int v8 = 0; v8 < 8; ++v8) {
    float facc[8];
#pragma unroll
    for (int e = 0; e < 8; ++e) facc[e] = 0.f;
    for (int cc = 0; cc < nc; ++cc) {
      bf16x8 pv = *(const bf16x8*)(pq + cc * 65536 + v8 * 8);
#pragma unroll
      for (int e = 0; e < 8; ++e) facc[e] += bf2f((unsigned short)pv[e]);
    }
#pragma unroll
    for (int e = 0; e < 8; ++e)
      outp[(size_t)(v8 * 8 + e) * Tn] = facc[e] * linv;
  }
}

// ---------------------------------------------------------------------------
extern "C" void kernel_launch(void* const* d_in, const int* in_sizes, int n_in,
                              void* d_out, int out_size, void* d_ws, size_t ws_size,
                              hipStream_t stream) {
  const float* x  = (const float*)d_in[0];
  const float* Wq = (const float*)d_in[1];
  const float* bq = (const float*)d_in[2];
  const float* Wk = (const float*)d_in[3];
  const float* bk = (const float*)d_in[4];
  const float* Wv = (const float*)d_in[5];
  const float* bv = (const float*)d_in[6];
  float* out = (float*)d_out;
  char* ws = (char*)d_ws;

  // layout (ends 63,209,472 B -- proven footprint):
  unsigned short* qb  = (unsigned short*)(ws);                //  8,388,608
  unsigned short* kbT = (unsigned short*)(ws + 8388608);      //  8,388,608
  unsigned short* vS  = (unsigned short*)(ws + 16777216);     //  8,388,608
  unsigned short* xt  = (unsigned short*)(ws + 25165824);     // 16,777,216 (dead after gemm)
  unsigned short* wt  = (unsigned short*)(ws + 41943040);     //    786,432 (dead after gemm)
  float*         bias = (float*)(ws + 42729472);              //      3,072 (dead after gemm)
  unsigned short* po  = (unsigned short*)(ws + 25165824);     // 37,748,736 = 288 x 128KB (overlaps xt/wt/bias)
  float*          mlb = (float*)(ws + 62914560);              //    294,912 (ends 63,209,472)

  prep_w_kernel<<<1536, 256, 0, stream>>>(Wq, Wk, Wv, bq, bk, bv, wt, bias);
  prep_x_kernel<<<dim3(64, 8, 4), 256, 0, stream>>>(x, out, xt);
  qkv_gemm_kernel<<<dim3(32, 6, 4), 256, 0, stream>>>(xt, wt, bias, qb, kbT, vS);
  attn_kernel<<<288, 512, 0, stream>>>(qb, kbT, vS, po, mlb);
  merge_kernel<<<dim3(16, 4, 4), 256, 0, stream>>>(po, mlb, out);
}